// Round 7
// baseline (176.282 us; speedup 1.0000x reference)
//
#include <hip/hip_runtime.h>
#include <math.h>

// ---------------------------------------------------------------------------
// Cosine_PredictingModule v7.
//   cat@W1 = heads@W1a + tails@W1b + cos*W1[128]  (per-node precompute).
//   Node record (one 128-B cache line): [64 B fp8 hn | 64 B fp8 P(+b1 cust)].
//   v7 NEW (edge kernel only): 8 lanes/edge — each node record is fetched by
//   ONE dwordx4 wave-instruction (lane g reads rec+g*16). 2 gather instrs
//   per edge (was 4). Lanes 0-3 carry hn, 4-7 carry P; shared fp8 decode,
//   masked partials, xor{1,2,4} reductions.
// ---------------------------------------------------------------------------

typedef __attribute__((ext_vector_type(8))) short bf16x8;
typedef __attribute__((ext_vector_type(4))) float f32x4;
typedef __attribute__((ext_vector_type(2))) float float2_t;
typedef __attribute__((ext_vector_type(8))) unsigned short ushort8_t;
typedef __attribute__((ext_vector_type(4))) float float4_t;
typedef __attribute__((ext_vector_type(4))) unsigned int uint4_t;
typedef __attribute__((ext_vector_type(2))) unsigned int uint2_t;

#define P_STRIDE 72   // acc-transpose LDS stride (ushorts)

__device__ __forceinline__ float bf2f(unsigned short u) {
    return __uint_as_float(((unsigned int)u) << 16);
}
__device__ __forceinline__ unsigned short f2bf(float f) {
    unsigned int x = __float_as_uint(f);
    return (unsigned short)((x + 0x7fffu + ((x >> 16) & 1u)) >> 16);
}

// K0: W1frag[half][nt][ks][lane][j] =
//   bf16(W1[half*64 + ks*32 + (lane>>4)*8 + j][nt*16 + (lane&15)])
__global__ __launch_bounds__(256) void prep_w1(
    const float* __restrict__ W1, unsigned short* __restrict__ frag)
{
    int idx = blockIdx.x * 256 + threadIdx.x;
    if (idx >= 2 * 4 * 2 * 64 * 8) return;
    int j    = idx & 7;
    int lane = (idx >> 3) & 63;
    int ks   = (idx >> 9) & 1;
    int nt   = (idx >> 10) & 3;
    int half = (idx >> 12) & 1;
    int k   = ks * 32 + (lane >> 4) * 8 + j;
    int col = nt * 16 + (lane & 15);
    frag[idx] = f2bf(W1[(half * 64 + k) * 64 + col]);
}

// K1: 64 nodes/block, 4 waves x 16 nodes. One barrier.
// rec: 128 B per node = [fp8 hn x64 | fp8 P x64].
__global__ __launch_bounds__(256) void node_fused(
    const float* __restrict__ hc, const float* __restrict__ hp,
    const unsigned short* __restrict__ w1frag, const float* __restrict__ b1,
    unsigned char* __restrict__ recC, unsigned char* __restrict__ recP,
    int nC, int nP, int blocksC)
{
    __shared__ unsigned short tile2[64 * P_STRIDE];  // 9.2 KB

    int b = blockIdx.x;
    const float* h; unsigned char* rec; int n, half;
    if (b < blocksC) { h = hc; rec = recC; n = nC; half = 0; }
    else { b -= blocksC; h = hp; rec = recP; n = nP; half = 1; }

    int node0 = b * 64;
    int nloc  = min(64, n - node0);
    int t     = threadIdx.x;
    int wave  = t >> 6, lane = t & 63;
    int m = lane & 15, quad = lane >> 4;

    if (wave * 16 < nloc) {
        int row = node0 + wave * 16 + m;   // nloc is a multiple of 16 here
        // Load h directly in MFMA A-fragment layout: 16 dims/lane.
        float4_t f[2][2];
#pragma unroll
        for (int ks = 0; ks < 2; ks++) {
            const float* srcp = h + (long)row * 64 + ks * 32 + quad * 8;
            f[ks][0] = *reinterpret_cast<const float4_t*>(srcp);
            f[ks][1] = *reinterpret_cast<const float4_t*>(srcp + 4);
        }

        // Row norm: this row's 64 dims live in lanes {m, m+16, m+32, m+48}.
        float ss = 0.f;
#pragma unroll
        for (int ks = 0; ks < 2; ks++)
#pragma unroll
            for (int i = 0; i < 2; i++)
#pragma unroll
                for (int j = 0; j < 4; j++) ss += f[ks][i][j] * f[ks][i][j];
        ss += __shfl_xor(ss, 16);
        ss += __shfl_xor(ss, 32);
        float inv = 1.f / fmaxf(sqrtf(ss), 1e-12f);

        // fp8 e4m3 normalized hn -> record bytes [ks*32+quad*8, +8).
#pragma unroll
        for (int ks = 0; ks < 2; ks++) {
            uint2_t u8;
#pragma unroll
            for (int i = 0; i < 2; i++) {
                unsigned int d = __builtin_amdgcn_cvt_pk_fp8_f32(
                    f[ks][i][0] * inv, f[ks][i][1] * inv, 0, false);
                d = __builtin_amdgcn_cvt_pk_fp8_f32(
                    f[ks][i][2] * inv, f[ks][i][3] * inv, d, true);
                u8[i] = d;
            }
            *reinterpret_cast<uint2_t*>(rec + (long)row * 128 + ks * 32 + quad * 8) = u8;
        }

        // A fragments (bf16) from registers.
        bf16x8 a[2];
#pragma unroll
        for (int ks = 0; ks < 2; ks++)
#pragma unroll
            for (int i = 0; i < 8; i++)
                a[ks][i] = (short)f2bf(f[ks][i >> 2][i & 3]);

        f32x4 acc[4];
#pragma unroll
        for (int nt = 0; nt < 4; nt++) acc[nt] = (f32x4){0.f, 0.f, 0.f, 0.f};
#pragma unroll
        for (int nt = 0; nt < 4; nt++)
#pragma unroll
            for (int ks = 0; ks < 2; ks++) {
                bf16x8 bf = *reinterpret_cast<const bf16x8*>(
                    &w1frag[(((half * 4 + nt) * 2 + ks) * 64 + lane) * 8]);
                acc[nt] = __builtin_amdgcn_mfma_f32_16x16x32_bf16(
                    a[ks], bf, acc[nt], 0, 0, 0);
            }
        if (half == 0) {     // fold b1 into customer-side P
#pragma unroll
            for (int nt = 0; nt < 4; nt++) {
                float bb = b1[nt * 16 + m];
#pragma unroll
                for (int r = 0; r < 4; r++) acc[nt][r] += bb;
            }
        }
        // C/D: col = lane&15, row = quad*4 + reg -> LDS transpose
#pragma unroll
        for (int nt = 0; nt < 4; nt++)
#pragma unroll
            for (int r = 0; r < 4; r++)
                tile2[(wave * 16 + quad * 4 + r) * P_STRIDE + nt * 16 + m]
                    = f2bf(acc[nt][r]);
    }
    __syncthreads();

    int nl = t >> 2, q = t & 3;
    if (nl < nloc) {   // P (fp8) -> record bytes [64 + q*16, +16), 16B store
        ushort8_t p0 = *reinterpret_cast<ushort8_t*>(&tile2[nl * P_STRIDE + q * 16]);
        ushort8_t p1 = *reinterpret_cast<ushort8_t*>(&tile2[nl * P_STRIDE + q * 16 + 8]);
        float v[16];
#pragma unroll
        for (int i = 0; i < 8; i++) { v[i] = bf2f(p0[i]); v[i + 8] = bf2f(p1[i]); }
        uint4_t u;
#pragma unroll
        for (int i = 0; i < 4; i++) {
            unsigned int d = __builtin_amdgcn_cvt_pk_fp8_f32(
                v[i * 4 + 0], v[i * 4 + 1], 0, false);
            d = __builtin_amdgcn_cvt_pk_fp8_f32(
                v[i * 4 + 2], v[i * 4 + 3], d, true);
            u[i] = d;
        }
        *reinterpret_cast<uint4_t*>(rec + (long)(node0 + nl) * 128 + 64 + q * 16) = u;
    }
}

// K2: one-shot, 8 lanes/edge, 8 edges/wave (32 edges per 256-thread block).
// Lane g reads rec+g*16: ONE dwordx4 instruction fetches a whole 128-B
// node record across 8 lanes. Lanes 0-3 hold hn halves, 4-7 hold P halves.
__global__ __launch_bounds__(256) void edge_mlp(
    const unsigned char* __restrict__ recC, const unsigned char* __restrict__ recP,
    const int* __restrict__ src, const int* __restrict__ dst,
    const float* __restrict__ W1, const float* __restrict__ W2,
    const float* __restrict__ b2, float* __restrict__ out, int nE)
{
    int lane = threadIdx.x & 63;
    int sub  = lane >> 3;      // edge within wave (0..7)
    int g    = lane & 7;       // lane within edge group
    int d0   = (g & 3) * 16;   // dim slice this lane covers (hn or P)
    int e    = ((blockIdx.x * 256 + threadIdx.x) >> 6) * 8 + sub;
    bool valid = e < nE;
    int s = valid ? src[e] : 0;
    int t = valid ? dst[e] : 0;

    // One 16-B load per lane per node record: 2 gather instrs per edge.
    uint4_t rsv = *reinterpret_cast<const uint4_t*>(recC + (long)s * 128 + g * 16);
    uint4_t rtv = *reinterpret_cast<const uint4_t*>(recP + (long)t * 128 + g * 16);

    // L1-hot parameter loads (only used by lanes g>=4, harmless elsewhere).
    float4_t w1v[4], w2v[4];
#pragma unroll
    for (int i = 0; i < 4; i++) {
        w1v[i] = *reinterpret_cast<const float4_t*>(W1 + 128 * 64 + d0 + i * 4);
        w2v[i] = *reinterpret_cast<const float4_t*>(W2 + d0 + i * 4);
    }
    float b2v = b2[0];

    // Shared fp8 decode: a = my 16 bytes of s-record, b = of t-record.
    float a[16], bb[16];
#pragma unroll
    for (int w = 0; w < 4; w++) {
        float2_t alo = __builtin_amdgcn_cvt_pk_f32_fp8((int)rsv[w], false);
        float2_t ahi = __builtin_amdgcn_cvt_pk_f32_fp8((int)rsv[w], true);
        float2_t blo = __builtin_amdgcn_cvt_pk_f32_fp8((int)rtv[w], false);
        float2_t bhi = __builtin_amdgcn_cvt_pk_f32_fp8((int)rtv[w], true);
        a[w*4+0] = alo[0]; a[w*4+1] = alo[1]; a[w*4+2] = ahi[0]; a[w*4+3] = ahi[1];
        bb[w*4+0] = blo[0]; bb[w*4+1] = blo[1]; bb[w*4+2] = bhi[0]; bb[w*4+3] = bhi[1];
    }

    // cos partial: only lanes g<4 hold hn data.
    float dot = 0.f;
#pragma unroll
    for (int i = 0; i < 16; i++) dot += a[i] * bb[i];
    dot = (g < 4) ? dot : 0.f;
    dot += __shfl_xor(dot, 1);
    dot += __shfl_xor(dot, 2);
    dot += __shfl_xor(dot, 4);
    float cosv = dot;                    // denom folded (≈1 to 1e-7)

    // MLP partial: only lanes g>=4 hold P data (a=Pc(+b1), bb=Pp).
    float p = 0.f;
#pragma unroll
    for (int i = 0; i < 16; i++) {
        float x = a[i] + bb[i] + cosv * w1v[i >> 2][i & 3];
        x = fmaxf(x, 0.f);
        p += x * w2v[i >> 2][i & 3];
    }
    p = (g >= 4) ? p : 0.f;
    p += __shfl_xor(p, 1);
    p += __shfl_xor(p, 2);
    p += __shfl_xor(p, 4);

    if (valid && g == 0)
        out[e] = 1.f / (1.f + expf(-(p + b2v)));
}

extern "C" void kernel_launch(void* const* d_in, const int* in_sizes, int n_in,
                              void* d_out, int out_size, void* d_ws, size_t ws_size,
                              hipStream_t stream) {
    const float* h_c = (const float*)d_in[0];
    const float* h_p = (const float*)d_in[1];
    const int*   src = (const int*)d_in[2];
    const int*   dst = (const int*)d_in[3];
    const float* W1  = (const float*)d_in[4];
    const float* b1  = (const float*)d_in[5];
    const float* W2  = (const float*)d_in[6];
    const float* b2  = (const float*)d_in[7];
    float* out = (float*)d_out;

    int nC = in_sizes[0] / 64;
    int nP = in_sizes[1] / 64;
    int nE = in_sizes[2];

    char* ws = (char*)d_ws;
    size_t off = 0;
    auto carve = [&](size_t bytes) {
        void* p = ws + off;
        off = (off + bytes + 255) & ~(size_t)255;
        return p;
    };
    unsigned char* recC = (unsigned char*)carve((size_t)nC * 128);
    unsigned char* recP = (unsigned char*)carve((size_t)nP * 128);
    unsigned short* w1f = (unsigned short*)carve((size_t)16384 * 2);

    prep_w1<<<64, 256, 0, stream>>>(W1, w1f);

    int blocksC = (nC + 63) / 64, blocksP = (nP + 63) / 64;
    node_fused<<<blocksC + blocksP, 256, 0, stream>>>(
        h_c, h_p, w1f, b1, recC, recP, nC, nP, blocksC);

    // 32 edges per block (8 edges/wave x 4 waves).
    edge_mlp<<<(nE + 31) / 32, 256, 0, stream>>>(
        recC, recP, src, dst, W1, W2, b2, out, nE);
}

// Round 8
// 148.174 us; speedup vs baseline: 1.1897x; 1.1897x over previous
//
#include <hip/hip_runtime.h>
#include <math.h>

// ---------------------------------------------------------------------------
// Cosine_PredictingModule v8.
//   cat@W1 = heads@W1a + tails@W1b + cos*W1[128]  (per-node precompute).
//   Node record (one 128-B line): [64 B fp8 hn | 64 B fp8 P(+b1 cust)].
//   K2 edge_mlp: exact v6 (4 lanes/edge, 16 edges/wave, 45.3 µs measured).
//   K1 node_fused v8: every global access coalesced —
//     A: thread t reads 16 contiguous fp32 (4xfloat4), norm via xor1/xor2,
//        writes bf16 A-tile + fp8 hn into LDS record staging.
//     B: MFMA from padded LDS tile, bf16 acc transpose to LDS.
//     C: P -> fp8 into LDS record staging.
//     D: block's 8 KB record region written with 2x16B/thread contiguous.
// ---------------------------------------------------------------------------

typedef __attribute__((ext_vector_type(8))) short bf16x8;
typedef __attribute__((ext_vector_type(4))) float f32x4;
typedef __attribute__((ext_vector_type(2))) float float2_t;
typedef __attribute__((ext_vector_type(8))) unsigned short ushort8_t;
typedef __attribute__((ext_vector_type(4))) float float4_t;
typedef __attribute__((ext_vector_type(4))) unsigned int uint4_t;
typedef __attribute__((ext_vector_type(2))) unsigned int uint2_t;

#define T_STRIDE 72   // A-tile LDS stride (ushorts), breaks 128B-power stride
#define P_STRIDE 72   // acc-transpose LDS stride (ushorts)

__device__ __forceinline__ float bf2f(unsigned short u) {
    return __uint_as_float(((unsigned int)u) << 16);
}
__device__ __forceinline__ unsigned short f2bf(float f) {
    unsigned int x = __float_as_uint(f);
    return (unsigned short)((x + 0x7fffu + ((x >> 16) & 1u)) >> 16);
}

// K0: W1frag[half][nt][ks][lane][j] =
//   bf16(W1[half*64 + ks*32 + (lane>>4)*8 + j][nt*16 + (lane&15)])
__global__ __launch_bounds__(256) void prep_w1(
    const float* __restrict__ W1, unsigned short* __restrict__ frag)
{
    int idx = blockIdx.x * 256 + threadIdx.x;
    if (idx >= 2 * 4 * 2 * 64 * 8) return;
    int j    = idx & 7;
    int lane = (idx >> 3) & 63;
    int ks   = (idx >> 9) & 1;
    int nt   = (idx >> 10) & 3;
    int half = (idx >> 12) & 1;
    int k   = ks * 32 + (lane >> 4) * 8 + j;
    int col = nt * 16 + (lane & 15);
    frag[idx] = f2bf(W1[(half * 64 + k) * 64 + col]);
}

// K1 v8: 64 nodes/block, all global traffic coalesced.
__global__ __launch_bounds__(256) void node_fused(
    const float* __restrict__ hc, const float* __restrict__ hp,
    const unsigned short* __restrict__ w1frag, const float* __restrict__ b1,
    unsigned char* __restrict__ recC, unsigned char* __restrict__ recP,
    int nC, int nP, int blocksC)
{
    __shared__ unsigned short tileA[64 * T_STRIDE];  // 9.2 KB bf16 h
    __shared__ unsigned short tile2[64 * P_STRIDE];  // 9.2 KB bf16 P^T
    __shared__ unsigned char  recs[64 * 128];        // 8 KB packed records

    int b = blockIdx.x;
    const float* h; unsigned char* rec; int n, half;
    if (b < blocksC) { h = hc; rec = recC; n = nC; half = 0; }
    else { b -= blocksC; h = hp; rec = recP; n = nP; half = 1; }

    int node0 = b * 64;
    int nloc  = min(64, n - node0);     // multiple of 16 for this problem
    int t     = threadIdx.x;
    int nl    = t >> 2, q = t & 3;      // node-local, 16-dim quarter
    int wave  = t >> 6, lane = t & 63;
    int m = lane & 15, quad = lane >> 4;

    // --- Phase A: coalesced fp32 read; norm; bf16 A-tile; fp8 hn -> recs.
    if (nl < nloc) {
        const float* srcp = h + (long)(node0 + nl) * 64 + q * 16;
        float4_t v[4];
#pragma unroll
        for (int i = 0; i < 4; i++)
            v[i] = *reinterpret_cast<const float4_t*>(srcp + i * 4);

        float ss = 0.f;
#pragma unroll
        for (int i = 0; i < 4; i++)
#pragma unroll
            for (int j = 0; j < 4; j++) ss += v[i][j] * v[i][j];
        ss += __shfl_xor(ss, 1);
        ss += __shfl_xor(ss, 2);                 // 4 lanes per node
        float inv = 1.f / fmaxf(sqrtf(ss), 1e-12f);

        // bf16 raw h -> A-tile
        ushort8_t u[2];
#pragma unroll
        for (int i = 0; i < 16; i++) u[i >> 3][i & 7] = f2bf(v[i >> 2][i & 3]);
        *reinterpret_cast<ushort8_t*>(&tileA[nl * T_STRIDE + q * 16])     = u[0];
        *reinterpret_cast<ushort8_t*>(&tileA[nl * T_STRIDE + q * 16 + 8]) = u[1];

        // fp8 e4m3 normalized hn -> record staging bytes [q*16, +16)
        uint4_t u8;
#pragma unroll
        for (int i = 0; i < 4; i++) {
            unsigned int d = __builtin_amdgcn_cvt_pk_fp8_f32(
                v[i][0] * inv, v[i][1] * inv, 0, false);
            d = __builtin_amdgcn_cvt_pk_fp8_f32(
                v[i][2] * inv, v[i][3] * inv, d, true);
            u8[i] = d;
        }
        *reinterpret_cast<uint4_t*>(&recs[nl * 128 + q * 16]) = u8;
    }
    __syncthreads();

    // --- Phase B: MFMA P = h @ W1half (+b1 cust); transpose into tile2.
    if (wave * 16 < nloc) {
        bf16x8 a[2];
#pragma unroll
        for (int ks = 0; ks < 2; ks++)
            a[ks] = *reinterpret_cast<const bf16x8*>(
                &tileA[(wave * 16 + m) * T_STRIDE + ks * 32 + quad * 8]);

        f32x4 acc[4];
#pragma unroll
        for (int nt = 0; nt < 4; nt++) acc[nt] = (f32x4){0.f, 0.f, 0.f, 0.f};
#pragma unroll
        for (int nt = 0; nt < 4; nt++)
#pragma unroll
            for (int ks = 0; ks < 2; ks++) {
                bf16x8 bf = *reinterpret_cast<const bf16x8*>(
                    &w1frag[(((half * 4 + nt) * 2 + ks) * 64 + lane) * 8]);
                acc[nt] = __builtin_amdgcn_mfma_f32_16x16x32_bf16(
                    a[ks], bf, acc[nt], 0, 0, 0);
            }
        if (half == 0) {     // fold b1 into customer-side P
#pragma unroll
            for (int nt = 0; nt < 4; nt++) {
                float bb = b1[nt * 16 + m];
#pragma unroll
                for (int r = 0; r < 4; r++) acc[nt][r] += bb;
            }
        }
        // C/D: col = lane&15, row = quad*4 + reg -> LDS transpose
#pragma unroll
        for (int nt = 0; nt < 4; nt++)
#pragma unroll
            for (int r = 0; r < 4; r++)
                tile2[(wave * 16 + quad * 4 + r) * P_STRIDE + nt * 16 + m]
                    = f2bf(acc[nt][r]);
    }
    __syncthreads();

    // --- Phase C: P -> fp8 into record staging bytes [64 + q*16, +16).
    if (nl < nloc) {
        ushort8_t p0 = *reinterpret_cast<ushort8_t*>(&tile2[nl * P_STRIDE + q * 16]);
        ushort8_t p1 = *reinterpret_cast<ushort8_t*>(&tile2[nl * P_STRIDE + q * 16 + 8]);
        float v[16];
#pragma unroll
        for (int i = 0; i < 8; i++) { v[i] = bf2f(p0[i]); v[i + 8] = bf2f(p1[i]); }
        uint4_t u;
#pragma unroll
        for (int i = 0; i < 4; i++) {
            unsigned int d = __builtin_amdgcn_cvt_pk_fp8_f32(
                v[i * 4 + 0], v[i * 4 + 1], 0, false);
            d = __builtin_amdgcn_cvt_pk_fp8_f32(
                v[i * 4 + 2], v[i * 4 + 3], d, true);
            u[i] = d;
        }
        *reinterpret_cast<uint4_t*>(&recs[nl * 128 + 64 + q * 16]) = u;
    }
    __syncthreads();

    // --- Phase D: fully-coalesced record write: thread t -> 32 B.
    if (t * 32 < nloc * 128) {
        uint4_t r0 = *reinterpret_cast<uint4_t*>(&recs[t * 32]);
        uint4_t r1 = *reinterpret_cast<uint4_t*>(&recs[t * 32 + 16]);
        unsigned char* dstp = rec + (long)node0 * 128 + t * 32;
        *reinterpret_cast<uint4_t*>(dstp)      = r0;
        *reinterpret_cast<uint4_t*>(dstp + 16) = r1;
    }
}

// K2: exact v6. One-shot, 4 lanes/edge, 16 edges/wave; 2 lines per edge.
__global__ __launch_bounds__(256) void edge_mlp(
    const unsigned char* __restrict__ recC, const unsigned char* __restrict__ recP,
    const int* __restrict__ src, const int* __restrict__ dst,
    const float* __restrict__ W1, const float* __restrict__ W2,
    const float* __restrict__ b2, float* __restrict__ out, int nE)
{
    int lane = threadIdx.x & 63;
    int sub  = lane >> 2;      // edge within wave (0..15)
    int g    = lane & 3;       // lane within edge group
    int d0   = g * 16;         // dims [d0, d0+16)
    int e    = ((blockIdx.x * 256 + threadIdx.x) >> 6) * 16 + sub;
    bool valid = e < nE;
    int s = valid ? src[e] : 0;
    int t = valid ? dst[e] : 0;

    // Gathers: 2x16B per node record (hn half + P half).
    const unsigned char* rs = recC + (long)s * 128;
    const unsigned char* rt = recP + (long)t * 128;
    uint4_t hs = *reinterpret_cast<const uint4_t*>(rs + d0);
    uint4_t ht = *reinterpret_cast<const uint4_t*>(rt + d0);
    uint4_t ps = *reinterpret_cast<const uint4_t*>(rs + 64 + d0);
    uint4_t pt = *reinterpret_cast<const uint4_t*>(rt + 64 + d0);

    // L1-hot parameter loads.
    float4_t w1v[4], w2v[4];
#pragma unroll
    for (int i = 0; i < 4; i++) {
        w1v[i] = *reinterpret_cast<const float4_t*>(W1 + 128 * 64 + d0 + i * 4);
        w2v[i] = *reinterpret_cast<const float4_t*>(W2 + d0 + i * 4);
    }
    float b2v = b2[0];

    // cosine partial dot (16 dims/lane).
    float dot = 0.f;
#pragma unroll
    for (int w = 0; w < 4; w++) {
        float2_t alo = __builtin_amdgcn_cvt_pk_f32_fp8((int)hs[w], false);
        float2_t ahi = __builtin_amdgcn_cvt_pk_f32_fp8((int)hs[w], true);
        float2_t blo = __builtin_amdgcn_cvt_pk_f32_fp8((int)ht[w], false);
        float2_t bhi = __builtin_amdgcn_cvt_pk_f32_fp8((int)ht[w], true);
        dot += alo[0] * blo[0] + alo[1] * blo[1] + ahi[0] * bhi[0] + ahi[1] * bhi[1];
    }
    dot += __shfl_xor(dot, 1);
    dot += __shfl_xor(dot, 2);
    float cosv = dot;                    // denom folded (≈1 to 1e-7)

    // MLP partial (16 dims/lane): x = relu(Pc+Pp+cos*w1l), p += x*w2.
    float p = 0.f;
#pragma unroll
    for (int w = 0; w < 4; w++) {
        float2_t clo = __builtin_amdgcn_cvt_pk_f32_fp8((int)ps[w], false);
        float2_t chi = __builtin_amdgcn_cvt_pk_f32_fp8((int)ps[w], true);
        float2_t dlo = __builtin_amdgcn_cvt_pk_f32_fp8((int)pt[w], false);
        float2_t dhi = __builtin_amdgcn_cvt_pk_f32_fp8((int)pt[w], true);
        float pcv[4] = {clo[0], clo[1], chi[0], chi[1]};
        float ppv[4] = {dlo[0], dlo[1], dhi[0], dhi[1]};
#pragma unroll
        for (int j = 0; j < 4; j++) {
            float x = pcv[j] + ppv[j] + cosv * w1v[w][j];   // b1 folded into Pc
            x = fmaxf(x, 0.f);
            p += x * w2v[w][j];
        }
    }
    p += __shfl_xor(p, 1);
    p += __shfl_xor(p, 2);

    if (valid && g == 0)
        out[e] = 1.f / (1.f + expf(-(p + b2v)));
}

extern "C" void kernel_launch(void* const* d_in, const int* in_sizes, int n_in,
                              void* d_out, int out_size, void* d_ws, size_t ws_size,
                              hipStream_t stream) {
    const float* h_c = (const float*)d_in[0];
    const float* h_p = (const float*)d_in[1];
    const int*   src = (const int*)d_in[2];
    const int*   dst = (const int*)d_in[3];
    const float* W1  = (const float*)d_in[4];
    const float* b1  = (const float*)d_in[5];
    const float* W2  = (const float*)d_in[6];
    const float* b2  = (const float*)d_in[7];
    float* out = (float*)d_out;

    int nC = in_sizes[0] / 64;
    int nP = in_sizes[1] / 64;
    int nE = in_sizes[2];

    char* ws = (char*)d_ws;
    size_t off = 0;
    auto carve = [&](size_t bytes) {
        void* p = ws + off;
        off = (off + bytes + 255) & ~(size_t)255;
        return p;
    };
    unsigned char* recC = (unsigned char*)carve((size_t)nC * 128);
    unsigned char* recP = (unsigned char*)carve((size_t)nP * 128);
    unsigned short* w1f = (unsigned short*)carve((size_t)16384 * 2);

    prep_w1<<<64, 256, 0, stream>>>(W1, w1f);

    int blocksC = (nC + 63) / 64, blocksP = (nP + 63) / 64;
    node_fused<<<blocksC + blocksP, 256, 0, stream>>>(
        h_c, h_p, w1f, b1, recC, recP, nC, nP, blocksC);

    // 64 edges per block (16 edges/wave x 4 waves).
    edge_mlp<<<(nE + 63) / 64, 256, 0, stream>>>(
        recC, recP, src, dst, W1, W2, b2, out, nE);
}

// Round 9
// 141.447 us; speedup vs baseline: 1.2463x; 1.0476x over previous
//
#include <hip/hip_runtime.h>
#include <math.h>

// ---------------------------------------------------------------------------
// Cosine_PredictingModule v9.
//   cat@W1 = heads@W1a + tails@W1b + cos*W1[128]  (per-node precompute).
//   Node record (one 128-B line): [64 B fp8 hn | 64 B fp8 P(+b1 cust)].
//   K1 node_fused: v8 (all global traffic coalesced).
//   K2 edge_mlp v9: 2 batches of 16 edges per wave (32 edges/wave); all 8
//      record gathers issued before compute -> 2x outstanding requests per
//      wave (Little's-law fix for the L3-latency-bound gather stream).
// ---------------------------------------------------------------------------

typedef __attribute__((ext_vector_type(8))) short bf16x8;
typedef __attribute__((ext_vector_type(4))) float f32x4;
typedef __attribute__((ext_vector_type(2))) float float2_t;
typedef __attribute__((ext_vector_type(8))) unsigned short ushort8_t;
typedef __attribute__((ext_vector_type(4))) float float4_t;
typedef __attribute__((ext_vector_type(4))) unsigned int uint4_t;
typedef __attribute__((ext_vector_type(2))) unsigned int uint2_t;

#define T_STRIDE 72   // A-tile LDS stride (ushorts)
#define P_STRIDE 72   // acc-transpose LDS stride (ushorts)

__device__ __forceinline__ float bf2f(unsigned short u) {
    return __uint_as_float(((unsigned int)u) << 16);
}
__device__ __forceinline__ unsigned short f2bf(float f) {
    unsigned int x = __float_as_uint(f);
    return (unsigned short)((x + 0x7fffu + ((x >> 16) & 1u)) >> 16);
}

// K0: W1frag[half][nt][ks][lane][j] =
//   bf16(W1[half*64 + ks*32 + (lane>>4)*8 + j][nt*16 + (lane&15)])
__global__ __launch_bounds__(256) void prep_w1(
    const float* __restrict__ W1, unsigned short* __restrict__ frag)
{
    int idx = blockIdx.x * 256 + threadIdx.x;
    if (idx >= 2 * 4 * 2 * 64 * 8) return;
    int j    = idx & 7;
    int lane = (idx >> 3) & 63;
    int ks   = (idx >> 9) & 1;
    int nt   = (idx >> 10) & 3;
    int half = (idx >> 12) & 1;
    int k   = ks * 32 + (lane >> 4) * 8 + j;
    int col = nt * 16 + (lane & 15);
    frag[idx] = f2bf(W1[(half * 64 + k) * 64 + col]);
}

// K1 v8: 64 nodes/block, all global traffic coalesced.
__global__ __launch_bounds__(256) void node_fused(
    const float* __restrict__ hc, const float* __restrict__ hp,
    const unsigned short* __restrict__ w1frag, const float* __restrict__ b1,
    unsigned char* __restrict__ recC, unsigned char* __restrict__ recP,
    int nC, int nP, int blocksC)
{
    __shared__ unsigned short tileA[64 * T_STRIDE];
    __shared__ unsigned short tile2[64 * P_STRIDE];
    __shared__ unsigned char  recs[64 * 128];

    int b = blockIdx.x;
    const float* h; unsigned char* rec; int n, half;
    if (b < blocksC) { h = hc; rec = recC; n = nC; half = 0; }
    else { b -= blocksC; h = hp; rec = recP; n = nP; half = 1; }

    int node0 = b * 64;
    int nloc  = min(64, n - node0);
    int t     = threadIdx.x;
    int nl    = t >> 2, q = t & 3;
    int wave  = t >> 6, lane = t & 63;
    int m = lane & 15, quad = lane >> 4;

    if (nl < nloc) {
        const float* srcp = h + (long)(node0 + nl) * 64 + q * 16;
        float4_t v[4];
#pragma unroll
        for (int i = 0; i < 4; i++)
            v[i] = *reinterpret_cast<const float4_t*>(srcp + i * 4);

        float ss = 0.f;
#pragma unroll
        for (int i = 0; i < 4; i++)
#pragma unroll
            for (int j = 0; j < 4; j++) ss += v[i][j] * v[i][j];
        ss += __shfl_xor(ss, 1);
        ss += __shfl_xor(ss, 2);
        float inv = 1.f / fmaxf(sqrtf(ss), 1e-12f);

        ushort8_t u[2];
#pragma unroll
        for (int i = 0; i < 16; i++) u[i >> 3][i & 7] = f2bf(v[i >> 2][i & 3]);
        *reinterpret_cast<ushort8_t*>(&tileA[nl * T_STRIDE + q * 16])     = u[0];
        *reinterpret_cast<ushort8_t*>(&tileA[nl * T_STRIDE + q * 16 + 8]) = u[1];

        uint4_t u8;
#pragma unroll
        for (int i = 0; i < 4; i++) {
            unsigned int d = __builtin_amdgcn_cvt_pk_fp8_f32(
                v[i][0] * inv, v[i][1] * inv, 0, false);
            d = __builtin_amdgcn_cvt_pk_fp8_f32(
                v[i][2] * inv, v[i][3] * inv, d, true);
            u8[i] = d;
        }
        *reinterpret_cast<uint4_t*>(&recs[nl * 128 + q * 16]) = u8;
    }
    __syncthreads();

    if (wave * 16 < nloc) {
        bf16x8 a[2];
#pragma unroll
        for (int ks = 0; ks < 2; ks++)
            a[ks] = *reinterpret_cast<const bf16x8*>(
                &tileA[(wave * 16 + m) * T_STRIDE + ks * 32 + quad * 8]);

        f32x4 acc[4];
#pragma unroll
        for (int nt = 0; nt < 4; nt++) acc[nt] = (f32x4){0.f, 0.f, 0.f, 0.f};
#pragma unroll
        for (int nt = 0; nt < 4; nt++)
#pragma unroll
            for (int ks = 0; ks < 2; ks++) {
                bf16x8 bf = *reinterpret_cast<const bf16x8*>(
                    &w1frag[(((half * 4 + nt) * 2 + ks) * 64 + lane) * 8]);
                acc[nt] = __builtin_amdgcn_mfma_f32_16x16x32_bf16(
                    a[ks], bf, acc[nt], 0, 0, 0);
            }
        if (half == 0) {
#pragma unroll
            for (int nt = 0; nt < 4; nt++) {
                float bb = b1[nt * 16 + m];
#pragma unroll
                for (int r = 0; r < 4; r++) acc[nt][r] += bb;
            }
        }
#pragma unroll
        for (int nt = 0; nt < 4; nt++)
#pragma unroll
            for (int r = 0; r < 4; r++)
                tile2[(wave * 16 + quad * 4 + r) * P_STRIDE + nt * 16 + m]
                    = f2bf(acc[nt][r]);
    }
    __syncthreads();

    if (nl < nloc) {
        ushort8_t p0 = *reinterpret_cast<ushort8_t*>(&tile2[nl * P_STRIDE + q * 16]);
        ushort8_t p1 = *reinterpret_cast<ushort8_t*>(&tile2[nl * P_STRIDE + q * 16 + 8]);
        float v[16];
#pragma unroll
        for (int i = 0; i < 8; i++) { v[i] = bf2f(p0[i]); v[i + 8] = bf2f(p1[i]); }
        uint4_t u;
#pragma unroll
        for (int i = 0; i < 4; i++) {
            unsigned int d = __builtin_amdgcn_cvt_pk_fp8_f32(
                v[i * 4 + 0], v[i * 4 + 1], 0, false);
            d = __builtin_amdgcn_cvt_pk_fp8_f32(
                v[i * 4 + 2], v[i * 4 + 3], d, true);
            u[i] = d;
        }
        *reinterpret_cast<uint4_t*>(&recs[nl * 128 + 64 + q * 16]) = u;
    }
    __syncthreads();

    if (t * 32 < nloc * 128) {
        uint4_t r0 = *reinterpret_cast<uint4_t*>(&recs[t * 32]);
        uint4_t r1 = *reinterpret_cast<uint4_t*>(&recs[t * 32 + 16]);
        unsigned char* dstp = rec + (long)node0 * 128 + t * 32;
        *reinterpret_cast<uint4_t*>(dstp)      = r0;
        *reinterpret_cast<uint4_t*>(dstp + 16) = r1;
    }
}

// K2 v9: 4 lanes/edge, 2 batches of 16 edges per wave (32 edges/wave).
// All 8 gathers issue before any compute -> 2x outstanding requests.
__global__ __launch_bounds__(256) void edge_mlp(
    const unsigned char* __restrict__ recC, const unsigned char* __restrict__ recP,
    const int* __restrict__ src, const int* __restrict__ dst,
    const float* __restrict__ W1, const float* __restrict__ W2,
    const float* __restrict__ b2, float* __restrict__ out, int nE)
{
    int lane = threadIdx.x & 63;
    int sub  = lane >> 2;      // edge slot within batch (0..15)
    int g    = lane & 3;       // lane within edge group
    int d0   = g * 16;         // dims [d0, d0+16)
    int wid  = (blockIdx.x * 256 + threadIdx.x) >> 6;

    int e0 = wid * 32 + sub;          // batch 0 edge
    int e1 = e0 + 16;                 // batch 1 edge
    bool v0 = e0 < nE, v1 = e1 < nE;
    int s0 = v0 ? src[e0] : 0, t0 = v0 ? dst[e0] : 0;
    int s1 = v1 ? src[e1] : 0, t1 = v1 ? dst[e1] : 0;

    // Issue all 8 record gathers up front.
    const unsigned char* rs0 = recC + (long)s0 * 128;
    const unsigned char* rt0 = recP + (long)t0 * 128;
    const unsigned char* rs1 = recC + (long)s1 * 128;
    const unsigned char* rt1 = recP + (long)t1 * 128;
    uint4_t hs0 = *reinterpret_cast<const uint4_t*>(rs0 + d0);
    uint4_t ht0 = *reinterpret_cast<const uint4_t*>(rt0 + d0);
    uint4_t ps0 = *reinterpret_cast<const uint4_t*>(rs0 + 64 + d0);
    uint4_t pt0 = *reinterpret_cast<const uint4_t*>(rt0 + 64 + d0);
    uint4_t hs1 = *reinterpret_cast<const uint4_t*>(rs1 + d0);
    uint4_t ht1 = *reinterpret_cast<const uint4_t*>(rt1 + d0);
    uint4_t ps1 = *reinterpret_cast<const uint4_t*>(rs1 + 64 + d0);
    uint4_t pt1 = *reinterpret_cast<const uint4_t*>(rt1 + 64 + d0);

    // L1-hot parameter loads.
    float4_t w1v[4], w2v[4];
#pragma unroll
    for (int i = 0; i < 4; i++) {
        w1v[i] = *reinterpret_cast<const float4_t*>(W1 + 128 * 64 + d0 + i * 4);
        w2v[i] = *reinterpret_cast<const float4_t*>(W2 + d0 + i * 4);
    }
    float b2v = b2[0];

#pragma unroll
    for (int batch = 0; batch < 2; batch++) {
        uint4_t hs = batch ? hs1 : hs0;
        uint4_t ht = batch ? ht1 : ht0;
        uint4_t ps = batch ? ps1 : ps0;
        uint4_t pt = batch ? pt1 : pt0;

        // cosine partial dot (16 dims/lane).
        float dot = 0.f;
#pragma unroll
        for (int w = 0; w < 4; w++) {
            float2_t alo = __builtin_amdgcn_cvt_pk_f32_fp8((int)hs[w], false);
            float2_t ahi = __builtin_amdgcn_cvt_pk_f32_fp8((int)hs[w], true);
            float2_t blo = __builtin_amdgcn_cvt_pk_f32_fp8((int)ht[w], false);
            float2_t bhi = __builtin_amdgcn_cvt_pk_f32_fp8((int)ht[w], true);
            dot += alo[0] * blo[0] + alo[1] * blo[1] + ahi[0] * bhi[0] + ahi[1] * bhi[1];
        }
        dot += __shfl_xor(dot, 1);
        dot += __shfl_xor(dot, 2);
        float cosv = dot;                // denom folded (≈1 to 1e-7)

        // MLP partial (16 dims/lane).
        float p = 0.f;
#pragma unroll
        for (int w = 0; w < 4; w++) {
            float2_t clo = __builtin_amdgcn_cvt_pk_f32_fp8((int)ps[w], false);
            float2_t chi = __builtin_amdgcn_cvt_pk_f32_fp8((int)ps[w], true);
            float2_t dlo = __builtin_amdgcn_cvt_pk_f32_fp8((int)pt[w], false);
            float2_t dhi = __builtin_amdgcn_cvt_pk_f32_fp8((int)pt[w], true);
            float pcv[4] = {clo[0], clo[1], chi[0], chi[1]};
            float ppv[4] = {dlo[0], dlo[1], dhi[0], dhi[1]};
#pragma unroll
            for (int j = 0; j < 4; j++) {
                float x = pcv[j] + ppv[j] + cosv * w1v[w][j];  // b1 folded
                x = fmaxf(x, 0.f);
                p += x * w2v[w][j];
            }
        }
        p += __shfl_xor(p, 1);
        p += __shfl_xor(p, 2);

        int e = batch ? e1 : e0;
        bool valid = batch ? v1 : v0;
        if (valid && g == 0)
            out[e] = 1.f / (1.f + expf(-(p + b2v)));
    }
}

extern "C" void kernel_launch(void* const* d_in, const int* in_sizes, int n_in,
                              void* d_out, int out_size, void* d_ws, size_t ws_size,
                              hipStream_t stream) {
    const float* h_c = (const float*)d_in[0];
    const float* h_p = (const float*)d_in[1];
    const int*   src = (const int*)d_in[2];
    const int*   dst = (const int*)d_in[3];
    const float* W1  = (const float*)d_in[4];
    const float* b1  = (const float*)d_in[5];
    const float* W2  = (const float*)d_in[6];
    const float* b2  = (const float*)d_in[7];
    float* out = (float*)d_out;

    int nC = in_sizes[0] / 64;
    int nP = in_sizes[1] / 64;
    int nE = in_sizes[2];

    char* ws = (char*)d_ws;
    size_t off = 0;
    auto carve = [&](size_t bytes) {
        void* p = ws + off;
        off = (off + bytes + 255) & ~(size_t)255;
        return p;
    };
    unsigned char* recC = (unsigned char*)carve((size_t)nC * 128);
    unsigned char* recP = (unsigned char*)carve((size_t)nP * 128);
    unsigned short* w1f = (unsigned short*)carve((size_t)16384 * 2);

    prep_w1<<<64, 256, 0, stream>>>(W1, w1f);

    int blocksC = (nC + 63) / 64, blocksP = (nP + 63) / 64;
    node_fused<<<blocksC + blocksP, 256, 0, stream>>>(
        h_c, h_p, w1f, b1, recC, recP, nC, nP, blocksC);

    // 128 edges per block (32 edges/wave x 4 waves).
    edge_mlp<<<(nE + 127) / 128, 256, 0, stream>>>(
        recC, recP, src, dst, W1, W2, b2, out, nE);
}